// Round 7
// baseline (70.128 us; speedup 1.0000x reference)
//
#include <hip/hip_runtime.h>

#define EPSF 1e-8f
#define FPB 4       // frames per group
#define BLOCK 256
#define PAIRS 2     // float2 atom-pairs per thread per chunk (4 atoms)
#define NSPLIT 2    // grid = 1024*2 = 2048 blocks = 8 blocks/CU

typedef float v2f __attribute__((ext_vector_type(2)));

// readfirstlane: uniform value -> SGPR-resident float
__device__ inline float rf(float v) {
    return __int_as_float(__builtin_amdgcn_readfirstlane(__float_as_int(v)));
}

// ---------- Kernel A: per-frame fused transform (VGPR-unconstrained) -------
// fr[f][0..2] = v = o_p - M*o_t ; fr[f][3..11] = M = Rp^T*Rt (row-major).
// |Rp(p-o_p) - Rt(t-o_t)| == |(p - v) - M*t| since Rp is orthonormal.
__device__ inline void compute_frame(const float* __restrict__ c, int f,
                                     float* __restrict__ o) {
    const float* p = c + 3 * f;
    float c0x = p[0], c0y = p[1], c0z = p[2];
    float c1x = p[3], c1y = p[4], c1z = p[5];
    float c2x = p[6], c2y = p[7], c2z = p[8];
    float e1x = c2x - c1x, e1y = c2y - c1y, e1z = c2z - c1z;
    float n1 = __builtin_amdgcn_sqrtf(e1x*e1x + e1y*e1y + e1z*e1z) + EPSF;
    float r1 = __builtin_amdgcn_rcpf(n1);
    e1x *= r1; e1y *= r1; e1z *= r1;
    float ax = c0x - c1x, ay = c0y - c1y, az = c0z - c1z;
    float d = ax*e1x + ay*e1y + az*e1z;
    ax -= d*e1x; ay -= d*e1y; az -= d*e1z;
    float n2 = __builtin_amdgcn_sqrtf(ax*ax + ay*ay + az*az) + EPSF;
    float r2 = __builtin_amdgcn_rcpf(n2);
    ax *= r2; ay *= r2; az *= r2;
    float bx = e1y*az - e1z*ay;
    float by = e1z*ax - e1x*az;
    float bz = e1x*ay - e1y*ax;
    o[0] = c1x; o[1]  = c1y; o[2]  = c1z;
    o[3] = e1x; o[4]  = e1y; o[5]  = e1z;
    o[6] = ax;  o[7]  = ay;  o[8]  = az;
    o[9] = bx;  o[10] = by;  o[11] = bz;
}

__global__ void frames_kernel(const float* __restrict__ pred,
                              const float* __restrict__ tru,
                              float* __restrict__ fr, int F, int Fpad) {
    int f = blockIdx.x * blockDim.x + threadIdx.x;   // 64-thread blocks
    if (f >= Fpad) return;
    float* D = fr + 12 * f;
    if (f < F) {
        float P[12], T[12], M[9];
        compute_frame(pred, f, P);
        compute_frame(tru,  f, T);
#pragma unroll
        for (int i = 0; i < 3; i++)
#pragma unroll
            for (int j = 0; j < 3; j++)
                M[3*i+j] = P[3+i]*T[3+j] + P[6+i]*T[6+j] + P[9+i]*T[9+j];
        D[0] = P[0] - (M[0]*T[0] + M[1]*T[1] + M[2]*T[2]);
        D[1] = P[1] - (M[3]*T[0] + M[4]*T[1] + M[5]*T[2]);
        D[2] = P[2] - (M[6]*T[0] + M[7]*T[1] + M[8]*T[2]);
#pragma unroll
        for (int j = 0; j < 9; j++) D[3+j] = M[j];
    } else {
        // finite identity pad; masked by w=0 in fape_main
        D[0]=0.f; D[1]=0.f; D[2]=0.f;
        D[3]=1.f; D[4]=0.f; D[5]=0.f;
        D[6]=0.f; D[7]=1.f; D[8]=0.f;
        D[9]=0.f; D[10]=0.f; D[11]=1.f;
    }
}

// ---------- Kernel B: hot loop — packed fp32 (v_pk_*), SGPR constants ------
__launch_bounds__(BLOCK, 8)
__global__ void fape_main(const float* __restrict__ pred,
                          const float* __restrict__ tru,
                          const float* __restrict__ fr,
                          float* __restrict__ part, int N, int F) {
    const int g = blockIdx.x >> 1;            // frame group (NSPLIT==2)
    const int s = blockIdx.x & (NSPLIT - 1);  // atom slice
    const int f0 = g * FPB;

    // 48 uniform frame constants -> SGPRs via readfirstlane
    float C[FPB][12];
#pragma unroll
    for (int i = 0; i < FPB; i++) {
        const float4* q = (const float4*)(fr + 12 * (f0 + i));  // 16B-aligned
        float4 qa = q[0], qb = q[1], qc = q[2];
        C[i][0] = rf(qa.x); C[i][1]  = rf(qa.y); C[i][2]  = rf(qa.z);
        C[i][3] = rf(qa.w); C[i][4]  = rf(qb.x); C[i][5]  = rf(qb.y);
        C[i][6] = rf(qb.z); C[i][7]  = rf(qb.w); C[i][8]  = rf(qc.x);
        C[i][9] = rf(qc.y); C[i][10] = rf(qc.z); C[i][11] = rf(qc.w);
    }

    float w[FPB];
    v2f acc[FPB];
#pragma unroll
    for (int i = 0; i < FPB; i++) {
        w[i] = (f0 + i < F) ? 1.0f : 0.0f;   // uniform
        acc[i] = (v2f)(0.0f);
    }

    // span = 2048 atoms; chunk = BLOCK * 2*PAIRS = 1024 atoms -> 2 chunks.
    const int span = N / NSPLIT;
    const int base = s * span;
    v2f px[PAIRS], py[PAIRS], pz[PAIRS], tx[PAIRS], ty[PAIRS], tz[PAIRS];
    for (int c = 0; c < span; c += BLOCK * 2 * PAIRS) {
#pragma unroll
        for (int k = 0; k < PAIRS; k++) {
            int n0 = base + c + threadIdx.x + (2 * k) * BLOCK;
            int n1 = n0 + BLOCK;
            const float* pp0 = pred + 3 * n0;
            const float* pp1 = pred + 3 * n1;
            px[k] = (v2f){pp0[0], pp1[0]};
            py[k] = (v2f){pp0[1], pp1[1]};
            pz[k] = (v2f){pp0[2], pp1[2]};
            const float* tp0 = tru + 3 * n0;
            const float* tp1 = tru + 3 * n1;
            tx[k] = (v2f){tp0[0], tp1[0]};
            ty[k] = (v2f){tp0[1], tp1[1]};
            tz[k] = (v2f){tp0[2], tp1[2]};
        }
#pragma unroll
        for (int i = 0; i < FPB; i++) {
#pragma unroll
            for (int k = 0; k < PAIRS; k++) {
                // c = (p - v) - M*t, two atoms per packed instruction
                v2f cx = __builtin_elementwise_fma((v2f)(-C[i][3]), tx[k],
                          __builtin_elementwise_fma((v2f)(-C[i][4]), ty[k],
                           __builtin_elementwise_fma((v2f)(-C[i][5]), tz[k],
                            px[k] - C[i][0])));
                v2f cy = __builtin_elementwise_fma((v2f)(-C[i][6]), tx[k],
                          __builtin_elementwise_fma((v2f)(-C[i][7]), ty[k],
                           __builtin_elementwise_fma((v2f)(-C[i][8]), tz[k],
                            py[k] - C[i][1])));
                v2f cz = __builtin_elementwise_fma((v2f)(-C[i][9]), tx[k],
                          __builtin_elementwise_fma((v2f)(-C[i][10]), ty[k],
                           __builtin_elementwise_fma((v2f)(-C[i][11]), tz[k],
                            pz[k] - C[i][2])));
                v2f d2 = __builtin_elementwise_fma(cz, cz,
                          __builtin_elementwise_fma(cy, cy,
                           __builtin_elementwise_fma(cx, cx, (v2f)(EPSF))));
                // sqrt has no packed form -> per-half
                v2f dist = {__builtin_amdgcn_sqrtf(d2.x),
                            __builtin_amdgcn_sqrtf(d2.y)};
                acc[i] += __builtin_elementwise_min(dist, (v2f)(10.0f));
            }
        }
    }

    float t = 0.0f;
#pragma unroll
    for (int i = 0; i < FPB; i++) t = fmaf(w[i], acc[i].x + acc[i].y, t);

    // wave reduce (64) -> cross-wave via LDS -> one plain store per block
#pragma unroll
    for (int off = 32; off > 0; off >>= 1) t += __shfl_down(t, off, 64);
    __shared__ float sred[BLOCK / 64];
    const int lane = threadIdx.x & 63;
    if (lane == 0) sred[threadIdx.x >> 6] = t;
    __syncthreads();
    if (threadIdx.x == 0) {
        float z = 0.0f;
#pragma unroll
        for (int i = 0; i < BLOCK / 64; i++) z += sred[i];
        part[blockIdx.x] = z;           // deterministic partials, no atomics
    }
}

// ---------- Kernel C: reduce 2048 partials, write the scalar ---------------
__global__ void reduce_kernel(const float* __restrict__ part,
                              float* __restrict__ out, int nb, float inv) {
    float s = 0.0f;
    for (int i = threadIdx.x; i < nb; i += BLOCK) s += part[i];
#pragma unroll
    for (int off = 32; off > 0; off >>= 1) s += __shfl_down(s, off, 64);
    __shared__ float sred[BLOCK / 64];
    const int lane = threadIdx.x & 63;
    if (lane == 0) sred[threadIdx.x >> 6] = s;
    __syncthreads();
    if (threadIdx.x == 0) {
        float z = 0.0f;
#pragma unroll
        for (int i = 0; i < BLOCK / 64; i++) z += sred[i];
        out[0] = z * inv;               // overwrites poison; no memset needed
    }
}

extern "C" void kernel_launch(void* const* d_in, const int* in_sizes, int n_in,
                              void* d_out, int out_size, void* d_ws, size_t ws_size,
                              hipStream_t stream) {
    const float* pred = (const float*)d_in[0];
    const float* tru  = (const float*)d_in[1];
    float* out = (float*)d_out;

    int N = in_sizes[0] / 3;            // 4096
    int F = N - 2;                      // 4094
    int groups = (F + FPB - 1) / FPB;   // 1024
    int Fpad = groups * FPB;            // 4096
    int gridB = groups * NSPLIT;        // 2048

    float* fr   = (float*)d_ws;                 // Fpad*12 floats (~197 KB)
    float* part = fr + (size_t)Fpad * 12;       // gridB floats

    // 64-thread blocks spread the latency-bound frame build over 64 CUs
    frames_kernel<<<Fpad / 64, 64, 0, stream>>>(pred, tru, fr, F, Fpad);

    fape_main<<<gridB, BLOCK, 0, stream>>>(pred, tru, fr, part, N, F);

    float inv = 1.0f / ((float)F * (float)N * 10.0f);
    reduce_kernel<<<1, BLOCK, 0, stream>>>(part, out, gridB, inv);
}